// Round 3
// baseline (228.132 us; speedup 1.0000x reference)
//
#include <hip/hip_runtime.h>

// WindowWarp: B=256, T=2048, C=64, WINDOW_RATIO=0.1, SCALES={0.5,2.0}
// WARP_SIZE = ceil(0.1*2048) = 205
// L_MAX = T - WARP_SIZE + int(WARP_SIZE*2.0) = 1843 + 410 = 2253
constexpr int Bn     = 256;
constexpr int Tn     = 2048;
constexpr int Cn     = 64;
constexpr int WARPSZ = 205;
constexpr int LMAX   = 2253;

// Native vector type for nontemporal stores (HIP's float4 is a class type,
// which __builtin_nontemporal_store rejects).
typedef float f32x4 __attribute__((ext_vector_type(4)));

// Map intermediate index j -> source position s -> (i0, i1, frac) into x rows.
__device__ __forceinline__ void map_j(float jf, float start, float nl, float rdenom,
                                      int& i0, int& i1, float& fr) {
    bool in_win = (jf >= start) && (jf < start + nl);
    bool after  = (jf >= start + nl);
    float s_win   = start + (jf - start) * rdenom;      // rdenom = (WARP-1)/max(nl-1,1)
    float s_after = jf - nl + (float)WARPSZ;
    float s = in_win ? s_win : (after ? s_after : jf);
    s = fminf(fmaxf(s, 0.0f), (float)(Tn - 1));
    float p0 = floorf(s);
    fr = s - p0;
    i0 = (int)p0;
    i1 = min(i0 + 1, Tn - 1);
}

__global__ __launch_bounds__(256) void window_warp_kernel(
        const float* __restrict__ x,
        const float* __restrict__ scales,
        const int*   __restrict__ starts,
        float*       __restrict__ out) {
    // Block geometry: 256 threads = 16 t-slots x 16 float4 column-groups,
    // 2 t-rows per thread (t0 and t0+16) -> 32 consecutive t per block.
    // 64 blocks per batch -> b is a pure function of blockIdx (wave-uniform:
    // scales[b]/starts[b] become s_load, batch bases stay in SGPRs).
    int b     = blockIdx.x >> 6;
    int tbase = ((blockIdx.x & 63) << 5) | (threadIdx.x >> 4);
    int cg    = threadIdx.x & 15;

    float scale = scales[b];
    float start = (float)starts[b];
    float nl    = floorf((float)WARPSZ * scale);        // new_len
    float Lm1   = (float)(Tn - WARPSZ) + nl - 1.0f;     // L - 1
    float rdenom = (float)(WARPSZ - 1) / fmaxf(nl - 1.0f, 1.0f);

    // Per-batch scalar bases; 32-bit element offsets (max 32767) from there.
    const f32x4* __restrict__ xb   = (const f32x4*)(x   + (size_t)b * (Tn * Cn));
    f32x4*       __restrict__ outb = (f32x4*)      (out + (size_t)b * (Tn * Cn));

    int   i00[2], i01[2], i10[2], i11[2];
    float f0[2], f1[2], fu[2];

    #pragma unroll
    for (int k = 0; k < 2; ++k) {
        int t = tbase + 16 * k;
        // Stage 2 (resample) index: u = t*(L-1)/(T-1), clipped to [0, L-1]
        float u = ((float)t * Lm1) / (float)(Tn - 1);
        u = fminf(fmaxf(u, 0.0f), Lm1);
        float q0 = floorf(u);
        fu[k] = u - q0;
        int j0 = (int)q0;
        int j1 = min(j0 + 1, LMAX - 1);
        map_j((float)j0, start, nl, rdenom, i00[k], i01[k], f0[k]);
        map_j((float)j1, start, nl, rdenom, i10[k], i11[k], f1[k]);
    }

    // Issue all 8 independent gathers before any consumption (2x MLP per wave
    // vs the 1-row version; compiler keeps them in flight together).
    f32x4 A0[2], A1[2], B0[2], B1[2];
    #pragma unroll
    for (int k = 0; k < 2; ++k) {
        A0[k] = xb[i00[k] * 16 + cg];
        A1[k] = xb[i01[k] * 16 + cg];
        B0[k] = xb[i10[k] * 16 + cg];
        B1[k] = xb[i11[k] * 16 + cg];
    }

    #pragma unroll
    for (int k = 0; k < 2; ++k) {
        int t = tbase + 16 * k;
        float g0 = 1.0f - f0[k], g1 = 1.0f - f1[k], gu = 1.0f - fu[k];
        f32x4 v0 = A0[k] * g0 + A1[k] * f0[k];
        f32x4 v1 = B0[k] * g1 + B1[k] * f1[k];
        f32x4 r  = v0 * gu + v1 * fu[k];
        // Output is write-once and never re-read: nontemporal store keeps the
        // streaming writes from evicting gather-reused x rows out of L1/L2.
        __builtin_nontemporal_store(r, &outb[t * 16 + cg]);
    }
}

extern "C" void kernel_launch(void* const* d_in, const int* in_sizes, int n_in,
                              void* d_out, int out_size, void* d_ws, size_t ws_size,
                              hipStream_t stream) {
    const float* x      = (const float*)d_in[0];
    const float* scales = (const float*)d_in[1];
    const int*   starts = (const int*)d_in[2];
    float* out = (float*)d_out;

    // B*T rows, 16 threads per row, 2 rows per thread -> B*T*8 threads
    int total_threads = Bn * Tn * (Cn / 4) / 2;
    int blocks = total_threads / 256;   // 16384; 64 blocks per batch
    window_warp_kernel<<<blocks, 256, 0, stream>>>(x, scales, starts, out);
}